// Round 5
// baseline (395.786 us; speedup 1.0000x reference)
//
#include <hip/hip_runtime.h>

#define CC 100000
#define DD 512

#define S_SCALE 30.0f
#define COS_M_C 0.8775825618903728f
#define SIN_M_C 0.479425538604203f
#define THRESH_C (-0.8775825618903728f)
#define MM_C 0.2397127693021015f

typedef __attribute__((ext_vector_type(8))) short short8;
typedef __attribute__((ext_vector_type(4))) float f32x4;

static __device__ __forceinline__ unsigned short f2bf(float x) {
  unsigned int u = __float_as_uint(x);
  unsigned int r = (u + 0x7fffu + ((u >> 16) & 1u)) >> 16;
  return (unsigned short)r;
}

#define FENCE() __builtin_amdgcn_sched_barrier(0)

// ---------------------------------------------------------------------------
// Kernel 1: per embedding row i (one wave per row): normalize, bf16, store to
// wsA in k-tiled + XOR-swizzled layout; compute target logit/ctm/ft.
// ---------------------------------------------------------------------------
__global__ __launch_bounds__(64) void k1_prep(
    const float* __restrict__ emb, const float* __restrict__ kern,
    const int* __restrict__ label, unsigned short* __restrict__ wsA,
    float* __restrict__ ws_target, float* __restrict__ ws_ctm,
    float* __restrict__ ws_ft) {
  const int i = blockIdx.x;
  const int l = threadIdx.x;

  const float4* er = reinterpret_cast<const float4*>(emb + (size_t)i * DD + l * 8);
  float4 v0 = er[0], v1 = er[1];
  float e[8] = {v0.x, v0.y, v0.z, v0.w, v1.x, v1.y, v1.z, v1.w};

  float esq = 0.f;
#pragma unroll
  for (int j = 0; j < 8; ++j) esq += e[j] * e[j];
#pragma unroll
  for (int o = 32; o > 0; o >>= 1) esq += __shfl_xor(esq, o);
  const float inv = rsqrtf(esq);

  const int c = label[i];
  float dot = 0.f, wsq = 0.f;
#pragma unroll
  for (int j = 0; j < 8; ++j) {
    float w = kern[(size_t)(l * 8 + j) * CC + c];
    dot += e[j] * w;
    wsq += w * w;
  }
#pragma unroll
  for (int o = 32; o > 0; o >>= 1) {
    dot += __shfl_xor(dot, o);
    wsq += __shfl_xor(wsq, o);
  }

  unsigned int pk[4];
#pragma unroll
  for (int j = 0; j < 4; ++j) {
    unsigned int lo = f2bf(e[2 * j] * inv);
    unsigned int hi = f2bf(e[2 * j + 1] * inv);
    pk[j] = lo | (hi << 16);
  }
  const int kb = l >> 2;
  const int off = kb * 32768 + i * 64 + ((16 * (l & 3)) ^ ((i & 3) << 4));
  uint4 v; v.x = pk[0]; v.y = pk[1]; v.z = pk[2]; v.w = pk[3];
  *reinterpret_cast<uint4*>(reinterpret_cast<char*>(wsA) + off) = v;

  if (l == 0) {
    float t = dot * rsqrtf(fmaxf(esq * wsq, 1e-30f));
    t = fminf(fmaxf(t, -1.f), 1.f);
    float st = sqrtf(fmaxf(0.f, 1.f - t * t));
    float ctm = t * COS_M_C - st * SIN_M_C;
    ws_target[i] = t;
    ws_ctm[i] = ctm;
    ws_ft[i] = (t > THRESH_C) ? ctm : (t - MM_C);
  }
}

// ---------------------------------------------------------------------------
// Kernel 2: deterministic reduction of 512 target logits -> t_new
// ---------------------------------------------------------------------------
__global__ __launch_bounds__(64) void k2_tnew(const float* __restrict__ ws_target,
                                              const float* __restrict__ t_in,
                                              float* __restrict__ ws_tnew) {
  const int l = threadIdx.x;
  float s = 0.f;
#pragma unroll
  for (int j = 0; j < 8; ++j) s += ws_target[l * 8 + j];
#pragma unroll
  for (int o = 32; o > 0; o >>= 1) s += __shfl_xor(s, o);
  if (l == 0) ws_tnew[0] = 0.01f * (s * (1.0f / 512.0f)) + 0.99f * t_in[0];
}

// ---------------------------------------------------------------------------
// Kernel 3: 512x64 tile GEMM + epilogue.
// Pipeline (fully unrolled, compile-time KT):
//   - B prefetch 2 tiles deep (bq[2][4], parity-indexed, constexpr)
//   - A gll double-buffered, 1 tile deep
//   - single counted wait per iter: vmcnt(8) at barrier2, AFTER issuing
//     B(kt+3)+A(kt+2) -> retires B(kt+2)+A(kt+1), each with a full
//     iteration of latency cover. BWRITE needs no wait (regs landed).
// In-flight trace (steady state, per wave): enter iter kt with
//   {B(kt+2), A(kt+1)} = 8 outstanding, B(kt+1) already in regs.
// ---------------------------------------------------------------------------
__global__ __launch_bounds__(512, 4) void k3_gemm(
    const float* __restrict__ kern, const unsigned short* __restrict__ wsA,
    const int* __restrict__ label, const float* __restrict__ ws_ctm,
    const float* __restrict__ ws_ft, const float* __restrict__ ws_tnew,
    float* __restrict__ out) {
  __shared__ __align__(16) unsigned short Alds[2][512 * 32];  // 2x32768 B
  __shared__ __align__(16) unsigned short Blds[2][64 * 32];   // 2x4096 B
  __shared__ float colsq[64];

  const int t = threadIdx.x;
  const int l = t & 63;
  const int wv = t >> 6;
  const int n0 = blockIdx.x * 64;

  if (t < 64) colsq[t] = 0.f;

  const int bn = l;
  const int gcol = n0 + bn;
  const bool colok = gcol < CC;
  const float* bcol = kern + gcol;

  float sumsq = 0.f;

  f32x4 acc[4][4];
#pragma unroll
  for (int a = 0; a < 4; ++a)
#pragma unroll
    for (int b = 0; b < 4; ++b) acc[a][b] = (f32x4){0.f, 0.f, 0.f, 0.f};

  const int lr = l & 15;
  const int lg = l >> 4;
  const int swz = (lg * 16) ^ ((lr & 3) << 4);
  char* Ab = reinterpret_cast<char*>(Alds);
  char* Bb = reinterpret_cast<char*>(Blds);

#define BLOAD(KT, r0, r1, r2, r3)                                        \
  {                                                                      \
    if (colok) {                                                         \
      const float* p_ = bcol + (size_t)((KT) * 32 + wv * 4) * CC;        \
      r0 = p_[0];                                                        \
      r1 = p_[(size_t)CC];                                               \
      r2 = p_[(size_t)2 * CC];                                           \
      r3 = p_[(size_t)3 * CC];                                           \
    } else {                                                             \
      r0 = r1 = r2 = r3 = 0.f;                                           \
    }                                                                    \
  }

#define AGLL(KT)                                                         \
  {                                                                      \
    const char* gA_ = reinterpret_cast<const char*>(wsA) + (KT) * 32768; \
    char* lA_ = Ab + ((KT)&1) * 32768;                                   \
    _Pragma("unroll") for (int i_ = 0; i_ < 4; ++i_) {                   \
      const int o_ = i_ * 8192 + t * 16;                                 \
      __builtin_amdgcn_global_load_lds(                                  \
          (const __attribute__((address_space(1))) unsigned int*)(gA_ + o_), \
          (__attribute__((address_space(3))) unsigned int*)(lA_ + o_),   \
          16, 0, 0);                                                     \
    }                                                                    \
  }

#define BWRITE(KT, r0, r1, r2, r3)                                       \
  {                                                                      \
    sumsq += r0 * r0 + r1 * r1 + r2 * r2 + r3 * r3;                      \
    uint2 pk_;                                                           \
    pk_.x = (unsigned int)f2bf(r0) | ((unsigned int)f2bf(r1) << 16);     \
    pk_.y = (unsigned int)f2bf(r2) | ((unsigned int)f2bf(r3) << 16);     \
    *reinterpret_cast<uint2*>(Bb + ((KT)&1) * 4096 + bn * 64 +           \
                              ((wv * 8) ^ ((bn & 3) << 4))) = pk_;       \
  }

  float bq[2][4];  // two loop-carried B register sets (parity (KT+1)&1)

  // ---- prologue ----
  float c0, c1, c2, c3;
  BLOAD(0, c0, c1, c2, c3);
  FENCE();
  AGLL(0);
  FENCE();
  BLOAD(1, bq[1][0], bq[1][1], bq[1][2], bq[1][3]);
  FENCE();
  AGLL(1);
  FENCE();
  BLOAD(2, bq[0][0], bq[0][1], bq[0][2], bq[0][3]);
  FENCE();
  // in-flight: B0,A0,B1,A1,B2 = 20
  asm volatile("s_waitcnt vmcnt(16)" ::: "memory");  // B0 landed
  BWRITE(0, c0, c1, c2, c3);
  FENCE();
  asm volatile("s_waitcnt vmcnt(8)" ::: "memory");  // A0, B1 landed
  asm volatile("s_waitcnt lgkmcnt(0)" ::: "memory");
  FENCE();
  __builtin_amdgcn_s_barrier();
  FENCE();
  // enter loop: in-flight {A1, B2} = 8; B1 in bq[1]

#define KBODY(KT)                                                          \
  {                                                                        \
    constexpr int cur_ = (KT)&1;                                           \
    constexpr int ws_ = ((KT) + 1) & 1;                                    \
    short8 af[4], bfr[4];                                                  \
    _Pragma("unroll") for (int mf = 0; mf < 4; ++mf) {                     \
      const int m = wv * 64 + mf * 16 + lr;                                \
      af[mf] =                                                             \
          *reinterpret_cast<const short8*>(Ab + cur_ * 32768 + m * 64 + swz); \
    }                                                                      \
    _Pragma("unroll") for (int nf = 0; nf < 4; ++nf) {                     \
      const int n = nf * 16 + lr;                                          \
      bfr[nf] =                                                            \
          *reinterpret_cast<const short8*>(Bb + cur_ * 4096 + n * 64 + swz);  \
    }                                                                      \
    if ((KT) < 15) {                                                       \
      BWRITE((KT) + 1, bq[ws_][0], bq[ws_][1], bq[ws_][2], bq[ws_][3]);    \
    }                                                                      \
    __builtin_amdgcn_s_setprio(1);                                         \
    _Pragma("unroll") for (int mf = 0; mf < 4; ++mf)                       \
        _Pragma("unroll") for (int nf = 0; nf < 4; ++nf) acc[mf][nf] =     \
        __builtin_amdgcn_mfma_f32_16x16x32_bf16(af[mf], bfr[nf],           \
                                                acc[mf][nf], 0, 0, 0);     \
    __builtin_amdgcn_s_setprio(0);                                         \
    asm volatile("s_waitcnt lgkmcnt(0)" ::: "memory");                     \
    FENCE();                                                               \
    __builtin_amdgcn_s_barrier();                                          \
    FENCE();                                                               \
    if ((KT) < 13) {                                                       \
      BLOAD((KT) + 3, bq[ws_][0], bq[ws_][1], bq[ws_][2], bq[ws_][3]);     \
      FENCE();                                                             \
    }                                                                      \
    if ((KT) < 14) {                                                       \
      AGLL((KT) + 2);                                                      \
      FENCE();                                                             \
    }                                                                      \
    if ((KT) < 13) {                                                       \
      asm volatile("s_waitcnt vmcnt(8)" ::: "memory");                     \
    } else if ((KT) == 13) {                                               \
      asm volatile("s_waitcnt vmcnt(4)" ::: "memory");                     \
    } else {                                                               \
      asm volatile("s_waitcnt vmcnt(0)" ::: "memory");                     \
    }                                                                      \
    FENCE();                                                               \
    __builtin_amdgcn_s_barrier();                                          \
    FENCE();                                                               \
  }

  KBODY(0) KBODY(1) KBODY(2) KBODY(3) KBODY(4) KBODY(5) KBODY(6) KBODY(7)
  KBODY(8) KBODY(9) KBODY(10) KBODY(11) KBODY(12) KBODY(13) KBODY(14)
  KBODY(15)

#undef KBODY

  // ---- column-norm reduce ----
  atomicAdd(&colsq[bn], sumsq);
  asm volatile("s_waitcnt lgkmcnt(0)" ::: "memory");
  FENCE();
  __builtin_amdgcn_s_barrier();
  FENCE();

  const float tnew = ws_tnew[0];
  float invn[4];
#pragma unroll
  for (int nf = 0; nf < 4; ++nf)
    invn[nf] = rsqrtf(fmaxf(colsq[nf * 16 + lr], 1e-30f));

  // ---- epilogue: transpose through wave-private LDS, float4 stores ----
  float* est = reinterpret_cast<float*>(Alds) + (size_t)wv * 1088;  // 16x68
  const int c4 = n0 + lr * 4;
#pragma unroll
  for (int mf = 0; mf < 4; ++mf) {
    asm volatile("s_waitcnt lgkmcnt(0)" ::: "memory");  // WAR vs prev reads
    FENCE();
#pragma unroll
    for (int r = 0; r < 4; ++r)
#pragma unroll
      for (int nf = 0; nf < 4; ++nf)
        est[(lg * 4 + r) * 68 + nf * 16 + lr] = acc[mf][nf][r] * invn[nf];
    asm volatile("s_waitcnt lgkmcnt(0)" ::: "memory");  // RAW: writes visible
    FENCE();
#pragma unroll
    for (int p = 0; p < 4; ++p) {
      const int rr = p * 4 + lg;
      const int m = wv * 64 + mf * 16 + rr;
      const float ctm = ws_ctm[m];
      const float ft = ws_ft[m];
      const int lab = label[m];
      float4 vv = *reinterpret_cast<const float4*>(&est[rr * 68 + lr * 4]);
      if (c4 < CC) {
        float ov[4] = {vv.x, vv.y, vv.z, vv.w};
#pragma unroll
        for (int j = 0; j < 4; ++j) {
          float cosv = fminf(fmaxf(ov[j], -1.f), 1.f);
          float val = (cosv > ctm) ? cosv * (tnew + cosv) : cosv;
          if (c4 + j == lab) val = ft;
          ov[j] = val * S_SCALE;
        }
        float4 st4;
        st4.x = ov[0]; st4.y = ov[1]; st4.z = ov[2]; st4.w = ov[3];
        *reinterpret_cast<float4*>(out + (size_t)m * CC + c4) = st4;
      }
    }
  }
#undef BLOAD
#undef AGLL
#undef BWRITE
}

// ---------------------------------------------------------------------------
extern "C" void kernel_launch(void* const* d_in, const int* in_sizes, int n_in,
                              void* d_out, int out_size, void* d_ws,
                              size_t ws_size, hipStream_t stream) {
  (void)in_sizes; (void)n_in; (void)out_size; (void)ws_size;
  const float* emb = (const float*)d_in[0];
  const float* kern = (const float*)d_in[1];
  const int* label = (const int*)d_in[2];
  const float* t_in = (const float*)d_in[3];
  float* out = (float*)d_out;

  char* ws = (char*)d_ws;
  unsigned short* wsA = (unsigned short*)ws;
  float* ws_target = (float*)(ws + 524288);
  float* ws_ctm = (float*)(ws + 526336);
  float* ws_ft = (float*)(ws + 528384);
  float* ws_tnew = (float*)(ws + 530432);

  k1_prep<<<512, 64, 0, stream>>>(emb, kern, label, wsA, ws_target, ws_ctm, ws_ft);
  k2_tnew<<<1, 64, 0, stream>>>(ws_target, t_in, ws_tnew);
  k3_gemm<<<(CC + 63) / 64, 512, 0, stream>>>(kern, wsA, label, ws_ctm, ws_ft,
                                              ws_tnew, out);
}

// Round 6
// 150.861 us; speedup vs baseline: 2.6235x; 2.6235x over previous
//
#include <hip/hip_runtime.h>

#define CC 100000
#define DD 512

#define S_SCALE 30.0f
#define COS_M_C 0.8775825618903728f
#define SIN_M_C 0.479425538604203f
#define THRESH_C (-0.8775825618903728f)
#define MM_C 0.2397127693021015f

typedef __attribute__((ext_vector_type(8))) short short8;
typedef __attribute__((ext_vector_type(4))) float f32x4;

static __device__ __forceinline__ unsigned short f2bf(float x) {
  unsigned int u = __float_as_uint(x);
  unsigned int r = (u + 0x7fffu + ((u >> 16) & 1u)) >> 16;
  return (unsigned short)r;
}

#define FENCE() __builtin_amdgcn_sched_barrier(0)

// ---------------------------------------------------------------------------
// Kernel 1: per embedding row i (one wave per row): normalize, bf16, store to
// wsA in k-tiled + XOR-swizzled layout; compute target logit/ctm/ft.
// ---------------------------------------------------------------------------
__global__ __launch_bounds__(64) void k1_prep(
    const float* __restrict__ emb, const float* __restrict__ kern,
    const int* __restrict__ label, unsigned short* __restrict__ wsA,
    float* __restrict__ ws_target, float* __restrict__ ws_ctm,
    float* __restrict__ ws_ft) {
  const int i = blockIdx.x;
  const int l = threadIdx.x;

  const float4* er = reinterpret_cast<const float4*>(emb + (size_t)i * DD + l * 8);
  float4 v0 = er[0], v1 = er[1];
  float e[8] = {v0.x, v0.y, v0.z, v0.w, v1.x, v1.y, v1.z, v1.w};

  float esq = 0.f;
#pragma unroll
  for (int j = 0; j < 8; ++j) esq += e[j] * e[j];
#pragma unroll
  for (int o = 32; o > 0; o >>= 1) esq += __shfl_xor(esq, o);
  const float inv = rsqrtf(esq);

  const int c = label[i];
  float dot = 0.f, wsq = 0.f;
#pragma unroll
  for (int j = 0; j < 8; ++j) {
    float w = kern[(size_t)(l * 8 + j) * CC + c];
    dot += e[j] * w;
    wsq += w * w;
  }
#pragma unroll
  for (int o = 32; o > 0; o >>= 1) {
    dot += __shfl_xor(dot, o);
    wsq += __shfl_xor(wsq, o);
  }

  unsigned int pk[4];
#pragma unroll
  for (int j = 0; j < 4; ++j) {
    unsigned int lo = f2bf(e[2 * j] * inv);
    unsigned int hi = f2bf(e[2 * j + 1] * inv);
    pk[j] = lo | (hi << 16);
  }
  const int kb = l >> 2;
  const int off = kb * 32768 + i * 64 + ((16 * (l & 3)) ^ ((i & 3) << 4));
  uint4 v; v.x = pk[0]; v.y = pk[1]; v.z = pk[2]; v.w = pk[3];
  *reinterpret_cast<uint4*>(reinterpret_cast<char*>(wsA) + off) = v;

  if (l == 0) {
    float t = dot * rsqrtf(fmaxf(esq * wsq, 1e-30f));
    t = fminf(fmaxf(t, -1.f), 1.f);
    float st = sqrtf(fmaxf(0.f, 1.f - t * t));
    float ctm = t * COS_M_C - st * SIN_M_C;
    ws_target[i] = t;
    ws_ctm[i] = ctm;
    ws_ft[i] = (t > THRESH_C) ? ctm : (t - MM_C);
  }
}

// ---------------------------------------------------------------------------
// Kernel 2: deterministic reduction of 512 target logits -> t_new
// ---------------------------------------------------------------------------
__global__ __launch_bounds__(64) void k2_tnew(const float* __restrict__ ws_target,
                                              const float* __restrict__ t_in,
                                              float* __restrict__ ws_tnew) {
  const int l = threadIdx.x;
  float s = 0.f;
#pragma unroll
  for (int j = 0; j < 8; ++j) s += ws_target[l * 8 + j];
#pragma unroll
  for (int o = 32; o > 0; o >>= 1) s += __shfl_xor(s, o);
  if (l == 0) ws_tnew[0] = 0.01f * (s * (1.0f / 512.0f)) + 0.99f * t_in[0];
}

// ---------------------------------------------------------------------------
// Kernel 3: 512x64 tile GEMM + epilogue. Round-4 structure (rolled loop,
// ONE loop-carried B register set — round 5's 2-deep/full-unroll spilled:
// +527MB scratch writes) with one reorder: BLOAD(kt+2) is issued at the TOP
// of iter kt (right after BWRITE(kt+1) frees the p regs), so B loads get a
// full iteration + MFMA cluster of latency cover instead of ~150 cy.
// Steady state per iter: enter with {B(kt+1),A(kt+1)}=8 outstanding;
//   vmcnt(4) retires B(kt+1) (iter-old, ~free); BWRITE; BLOAD(kt+2);
//   MFMA; lgkm0; barrier1; AGLL(kt+2); vmcnt(8) retires A(kt+1) (iter-old);
//   barrier2.
// ---------------------------------------------------------------------------
__global__ __launch_bounds__(512, 4) void k3_gemm(
    const float* __restrict__ kern, const unsigned short* __restrict__ wsA,
    const int* __restrict__ label, const float* __restrict__ ws_ctm,
    const float* __restrict__ ws_ft, const float* __restrict__ ws_tnew,
    float* __restrict__ out) {
  __shared__ __align__(16) unsigned short Alds[2][512 * 32];  // 2x32768 B
  __shared__ __align__(16) unsigned short Blds[2][64 * 32];   // 2x4096 B
  __shared__ float colsq[64];

  const int t = threadIdx.x;
  const int l = t & 63;
  const int wv = t >> 6;
  const int n0 = blockIdx.x * 64;

  if (t < 64) colsq[t] = 0.f;

  const int bn = l;
  const int gcol = n0 + bn;
  const bool colok = gcol < CC;
  const float* bcol = kern + gcol;

  float sumsq = 0.f;

  f32x4 acc[4][4];
#pragma unroll
  for (int a = 0; a < 4; ++a)
#pragma unroll
    for (int b = 0; b < 4; ++b) acc[a][b] = (f32x4){0.f, 0.f, 0.f, 0.f};

  const int lr = l & 15;
  const int lg = l >> 4;
  const int swz = (lg * 16) ^ ((lr & 3) << 4);
  char* Ab = reinterpret_cast<char*>(Alds);
  char* Bb = reinterpret_cast<char*>(Blds);

#define BLOAD(KT, r0, r1, r2, r3)                                        \
  {                                                                      \
    if (colok) {                                                         \
      const float* p_ = bcol + (size_t)((KT) * 32 + wv * 4) * CC;        \
      r0 = p_[0];                                                        \
      r1 = p_[(size_t)CC];                                               \
      r2 = p_[(size_t)2 * CC];                                           \
      r3 = p_[(size_t)3 * CC];                                           \
    } else {                                                             \
      r0 = r1 = r2 = r3 = 0.f;                                           \
    }                                                                    \
  }

#define AGLL(KT)                                                         \
  {                                                                      \
    const char* gA_ = reinterpret_cast<const char*>(wsA) + (KT) * 32768; \
    char* lA_ = Ab + ((KT)&1) * 32768;                                   \
    _Pragma("unroll") for (int i_ = 0; i_ < 4; ++i_) {                   \
      const int o_ = i_ * 8192 + t * 16;                                 \
      __builtin_amdgcn_global_load_lds(                                  \
          (const __attribute__((address_space(1))) unsigned int*)(gA_ + o_), \
          (__attribute__((address_space(3))) unsigned int*)(lA_ + o_),   \
          16, 0, 0);                                                     \
    }                                                                    \
  }

#define BWRITE(KT, r0, r1, r2, r3)                                       \
  {                                                                      \
    sumsq += r0 * r0 + r1 * r1 + r2 * r2 + r3 * r3;                      \
    uint2 pk_;                                                           \
    pk_.x = (unsigned int)f2bf(r0) | ((unsigned int)f2bf(r1) << 16);     \
    pk_.y = (unsigned int)f2bf(r2) | ((unsigned int)f2bf(r3) << 16);     \
    *reinterpret_cast<uint2*>(Bb + ((KT)&1) * 4096 + bn * 64 +           \
                              ((wv * 8) ^ ((bn & 3) << 4))) = pk_;       \
  }

  // ---- prologue ----
  float c0, c1, c2, c3;  // B(0)
  float p0, p1, p2, p3;  // B(kt+1), loop-carried (single set)
  BLOAD(0, c0, c1, c2, c3);
  FENCE();
  AGLL(0);
  FENCE();
  BLOAD(1, p0, p1, p2, p3);
  FENCE();
  AGLL(1);
  FENCE();
  // in-flight: B0,A0,B1,A1 = 16
  asm volatile("s_waitcnt vmcnt(12)" ::: "memory");  // B0 landed
  BWRITE(0, c0, c1, c2, c3);
  FENCE();
  asm volatile("s_waitcnt vmcnt(8)" ::: "memory");  // A0 landed; {B1,A1} left
  asm volatile("s_waitcnt lgkmcnt(0)" ::: "memory");
  FENCE();
  __builtin_amdgcn_s_barrier();
  FENCE();
  // enter loop: in-flight {B1, A1} = 8 (B older than A)

  for (int kt = 0; kt < 16; ++kt) {
    const int cur = kt & 1;
    // fragment reads from current buffers
    short8 af[4], bfr[4];
#pragma unroll
    for (int mf = 0; mf < 4; ++mf) {
      const int m = wv * 64 + mf * 16 + lr;
      af[mf] = *reinterpret_cast<const short8*>(Ab + cur * 32768 + m * 64 + swz);
    }
#pragma unroll
    for (int nf = 0; nf < 4; ++nf) {
      const int n = nf * 16 + lr;
      bfr[nf] = *reinterpret_cast<const short8*>(Bb + cur * 4096 + n * 64 + swz);
    }
    // commit B(kt+1): its loads are a full iteration old -> vmcnt ~free
    if (kt < 15) {
      asm volatile("s_waitcnt vmcnt(4)" ::: "memory");
      BWRITE(kt + 1, p0, p1, p2, p3);
      FENCE();
    }
    // issue B(kt+2) now: full iter + MFMA cluster of cover before use
    if (kt < 14) {
      BLOAD(kt + 2, p0, p1, p2, p3);
      FENCE();
    }
    __builtin_amdgcn_s_setprio(1);
#pragma unroll
    for (int mf = 0; mf < 4; ++mf)
#pragma unroll
      for (int nf = 0; nf < 4; ++nf)
        acc[mf][nf] = __builtin_amdgcn_mfma_f32_16x16x32_bf16(
            af[mf], bfr[nf], acc[mf][nf], 0, 0, 0);
    __builtin_amdgcn_s_setprio(0);
    asm volatile("s_waitcnt lgkmcnt(0)" ::: "memory");
    FENCE();
    __builtin_amdgcn_s_barrier();  // all waves done reading bufs[cur]
    FENCE();
    // refill A into the just-released buffer; release A(kt+1)
    if (kt < 14) {
      AGLL(kt + 2);
      FENCE();
      asm volatile("s_waitcnt vmcnt(8)" ::: "memory");  // A(kt+1) landed
    } else {
      asm volatile("s_waitcnt vmcnt(0)" ::: "memory");
    }
    FENCE();
    __builtin_amdgcn_s_barrier();
    FENCE();
  }

  // ---- column-norm reduce ----
  atomicAdd(&colsq[bn], sumsq);
  asm volatile("s_waitcnt lgkmcnt(0)" ::: "memory");
  FENCE();
  __builtin_amdgcn_s_barrier();
  FENCE();

  const float tnew = ws_tnew[0];
  float invn[4];
#pragma unroll
  for (int nf = 0; nf < 4; ++nf)
    invn[nf] = rsqrtf(fmaxf(colsq[nf * 16 + lr], 1e-30f));

  // ---- epilogue: transpose through wave-private LDS, float4 stores ----
  float* est = reinterpret_cast<float*>(Alds) + (size_t)wv * 1088;  // 16x68
  const int c4 = n0 + lr * 4;
#pragma unroll
  for (int mf = 0; mf < 4; ++mf) {
    asm volatile("s_waitcnt lgkmcnt(0)" ::: "memory");  // WAR vs prev reads
    FENCE();
#pragma unroll
    for (int r = 0; r < 4; ++r)
#pragma unroll
      for (int nf = 0; nf < 4; ++nf)
        est[(lg * 4 + r) * 68 + nf * 16 + lr] = acc[mf][nf][r] * invn[nf];
    asm volatile("s_waitcnt lgkmcnt(0)" ::: "memory");  // RAW: writes visible
    FENCE();
#pragma unroll
    for (int p = 0; p < 4; ++p) {
      const int rr = p * 4 + lg;
      const int m = wv * 64 + mf * 16 + rr;
      const float ctm = ws_ctm[m];
      const float ft = ws_ft[m];
      const int lab = label[m];
      float4 vv = *reinterpret_cast<const float4*>(&est[rr * 68 + lr * 4]);
      if (c4 < CC) {
        float ov[4] = {vv.x, vv.y, vv.z, vv.w};
#pragma unroll
        for (int j = 0; j < 4; ++j) {
          float cosv = fminf(fmaxf(ov[j], -1.f), 1.f);
          float val = (cosv > ctm) ? cosv * (tnew + cosv) : cosv;
          if (c4 + j == lab) val = ft;
          ov[j] = val * S_SCALE;
        }
        float4 st4;
        st4.x = ov[0]; st4.y = ov[1]; st4.z = ov[2]; st4.w = ov[3];
        *reinterpret_cast<float4*>(out + (size_t)m * CC + c4) = st4;
      }
    }
  }
#undef BLOAD
#undef AGLL
#undef BWRITE
}

// ---------------------------------------------------------------------------
extern "C" void kernel_launch(void* const* d_in, const int* in_sizes, int n_in,
                              void* d_out, int out_size, void* d_ws,
                              size_t ws_size, hipStream_t stream) {
  (void)in_sizes; (void)n_in; (void)out_size; (void)ws_size;
  const float* emb = (const float*)d_in[0];
  const float* kern = (const float*)d_in[1];
  const int* label = (const int*)d_in[2];
  const float* t_in = (const float*)d_in[3];
  float* out = (float*)d_out;

  char* ws = (char*)d_ws;
  unsigned short* wsA = (unsigned short*)ws;
  float* ws_target = (float*)(ws + 524288);
  float* ws_ctm = (float*)(ws + 526336);
  float* ws_ft = (float*)(ws + 528384);
  float* ws_tnew = (float*)(ws + 530432);

  k1_prep<<<512, 64, 0, stream>>>(emb, kern, label, wsA, ws_target, ws_ctm, ws_ft);
  k2_tnew<<<1, 64, 0, stream>>>(ws_target, t_in, ws_tnew);
  k3_gemm<<<(CC + 63) / 64, 512, 0, stream>>>(kern, wsA, label, ws_ctm, ws_ft,
                                              ws_tnew, out);
}

// Round 7
// 150.851 us; speedup vs baseline: 2.6237x; 1.0001x over previous
//
#include <hip/hip_runtime.h>

#define CC 100000
#define DD 512

#define S_SCALE 30.0f
#define COS_M_C 0.8775825618903728f
#define SIN_M_C 0.479425538604203f
#define THRESH_C (-0.8775825618903728f)
#define MM_C 0.2397127693021015f

typedef __attribute__((ext_vector_type(8))) short short8;
typedef __attribute__((ext_vector_type(4))) float f32x4;

static __device__ __forceinline__ unsigned short f2bf(float x) {
  unsigned int u = __float_as_uint(x);
  unsigned int r = (u + 0x7fffu + ((u >> 16) & 1u)) >> 16;
  return (unsigned short)r;
}

#define FENCE() __builtin_amdgcn_sched_barrier(0)

// Chunk swizzle: 16B chunk c of row r holds k-slice s = c ^ (r&3) ^ ((r>>2)&3).
// (Involution; adds the (r>>2) bit the old swizzle lacked, so same-lg lanes
//  l and l+4 no longer alias the same banks -> conflict-free b128 reads.)

// ---------------------------------------------------------------------------
// Kernel 1: per embedding row i (one wave per row): normalize, bf16, store to
// wsA in k-tiled + chunk-swizzled layout; compute target logit/ctm/ft.
// ---------------------------------------------------------------------------
__global__ __launch_bounds__(64) void k1_prep(
    const float* __restrict__ emb, const float* __restrict__ kern,
    const int* __restrict__ label, unsigned short* __restrict__ wsA,
    float* __restrict__ ws_target, float* __restrict__ ws_ctm,
    float* __restrict__ ws_ft) {
  const int i = blockIdx.x;
  const int l = threadIdx.x;

  const float4* er = reinterpret_cast<const float4*>(emb + (size_t)i * DD + l * 8);
  float4 v0 = er[0], v1 = er[1];
  float e[8] = {v0.x, v0.y, v0.z, v0.w, v1.x, v1.y, v1.z, v1.w};

  float esq = 0.f;
#pragma unroll
  for (int j = 0; j < 8; ++j) esq += e[j] * e[j];
#pragma unroll
  for (int o = 32; o > 0; o >>= 1) esq += __shfl_xor(esq, o);
  const float inv = rsqrtf(esq);

  const int c = label[i];
  float dot = 0.f, wsq = 0.f;
#pragma unroll
  for (int j = 0; j < 8; ++j) {
    float w = kern[(size_t)(l * 8 + j) * CC + c];
    dot += e[j] * w;
    wsq += w * w;
  }
#pragma unroll
  for (int o = 32; o > 0; o >>= 1) {
    dot += __shfl_xor(dot, o);
    wsq += __shfl_xor(wsq, o);
  }

  unsigned int pk[4];
#pragma unroll
  for (int j = 0; j < 4; ++j) {
    unsigned int lo = f2bf(e[2 * j] * inv);
    unsigned int hi = f2bf(e[2 * j + 1] * inv);
    pk[j] = lo | (hi << 16);
  }
  const int kb = l >> 2;  // k-block (32 wide); lane holds k-slice s = l&3
  const int chunk = (l & 3) ^ (i & 3) ^ ((i >> 2) & 3);
  const int off = kb * 32768 + i * 64 + (chunk << 4);
  uint4 v; v.x = pk[0]; v.y = pk[1]; v.z = pk[2]; v.w = pk[3];
  *reinterpret_cast<uint4*>(reinterpret_cast<char*>(wsA) + off) = v;

  if (l == 0) {
    float t = dot * rsqrtf(fmaxf(esq * wsq, 1e-30f));
    t = fminf(fmaxf(t, -1.f), 1.f);
    float st = sqrtf(fmaxf(0.f, 1.f - t * t));
    float ctm = t * COS_M_C - st * SIN_M_C;
    ws_target[i] = t;
    ws_ctm[i] = ctm;
    ws_ft[i] = (t > THRESH_C) ? ctm : (t - MM_C);
  }
}

// ---------------------------------------------------------------------------
// Kernel 2: deterministic reduction of 512 target logits -> t_new
// ---------------------------------------------------------------------------
__global__ __launch_bounds__(64) void k2_tnew(const float* __restrict__ ws_target,
                                              const float* __restrict__ t_in,
                                              float* __restrict__ ws_tnew) {
  const int l = threadIdx.x;
  float s = 0.f;
#pragma unroll
  for (int j = 0; j < 8; ++j) s += ws_target[l * 8 + j];
#pragma unroll
  for (int o = 32; o > 0; o >>= 1) s += __shfl_xor(s, o);
  if (l == 0) ws_tnew[0] = 0.01f * (s * (1.0f / 512.0f)) + 0.99f * t_in[0];
}

// ---------------------------------------------------------------------------
// Kernel 3: 512x64 tile GEMM + epilogue, ONE barrier per K-iter.
//  - A staging is WAVE-PRIVATE: wave wv glls only its own 64-row (4 KB)
//    chunk, so A needs no barrier, only wave-local counted vmcnt (2-iter
//    cover) and a wave-local lgkmcnt(0) before overwriting the buffer it
//    just read.
//  - B (cross-wave k-slices) keeps the single barrier: readers drain reads
//    (lgkm) before arriving, writers write the opposite buffer after
//    leaving -> one barrier separates them in both directions.
//  - All LDS rows use the (r&3)^((r>>2)&3) chunk swizzle -> conflict-free
//    ds_read_b128 / ds_write.
// Steady-state queue per wave at iter entry: [B(kt+1):4, A(kt+1):4].
//   vmcnt(4) -> B regs; BWRITE(kt+1); BLOAD(kt+2); lgkm0; AGLL(kt+2);
//   MFMA; barrier; vmcnt(8) -> A(kt+1). Tail: kt=14 vmcnt(0), kt=15 bare.
// ---------------------------------------------------------------------------
__global__ __launch_bounds__(512, 4) void k3_gemm(
    const float* __restrict__ kern, const unsigned short* __restrict__ wsA,
    const int* __restrict__ label, const float* __restrict__ ws_ctm,
    const float* __restrict__ ws_ft, const float* __restrict__ ws_tnew,
    float* __restrict__ out) {
  __shared__ __align__(16) unsigned short Alds[2][512 * 32];  // 2x32768 B
  __shared__ __align__(16) unsigned short Blds[2][64 * 32];   // 2x4096 B
  __shared__ float colsq[64];

  const int t = threadIdx.x;
  const int l = t & 63;
  const int wv = t >> 6;
  const int n0 = blockIdx.x * 64;

  if (t < 64) colsq[t] = 0.f;

  const int bn = l;
  const int gcol = n0 + bn;
  const bool colok = gcol < CC;
  const float* bcol = kern + gcol;

  float sumsq = 0.f;

  f32x4 acc[4][4];
#pragma unroll
  for (int a = 0; a < 4; ++a)
#pragma unroll
    for (int b = 0; b < 4; ++b) acc[a][b] = (f32x4){0.f, 0.f, 0.f, 0.f};

  const int lr = l & 15;
  const int lg = l >> 4;
  // read swizzle: want k-slice lg of row (..+lr): chunk = lg^(lr&3)^((lr>>2)&3)
  const int swz = ((lg ^ (lr & 3) ^ ((lr >> 2) & 3)) << 4);
  char* Ab = reinterpret_cast<char*>(Alds);
  char* Bb = reinterpret_cast<char*>(Blds);

#define BLOAD(KT, r0, r1, r2, r3)                                        \
  {                                                                      \
    if (colok) {                                                         \
      const float* p_ = bcol + (size_t)((KT) * 32 + wv * 4) * CC;        \
      r0 = p_[0];                                                        \
      r1 = p_[(size_t)CC];                                               \
      r2 = p_[(size_t)2 * CC];                                           \
      r3 = p_[(size_t)3 * CC];                                           \
    } else {                                                             \
      r0 = r1 = r2 = r3 = 0.f;                                           \
    }                                                                    \
  }

// wave-private A staging: wave wv copies its own 4 KB (rows wv*64..+63)
#define AGLL(KT)                                                         \
  {                                                                      \
    const char* gA_ =                                                    \
        reinterpret_cast<const char*>(wsA) + (KT) * 32768 + wv * 4096;   \
    char* lA_ = Ab + ((KT)&1) * 32768 + wv * 4096;                       \
    _Pragma("unroll") for (int i_ = 0; i_ < 4; ++i_) {                   \
      const int o_ = i_ * 1024 + l * 16;                                 \
      __builtin_amdgcn_global_load_lds(                                  \
          (const __attribute__((address_space(1))) unsigned int*)(gA_ + o_), \
          (__attribute__((address_space(3))) unsigned int*)(lA_ + o_),   \
          16, 0, 0);                                                     \
    }                                                                    \
  }

// wave wv writes 8 B of row bn at k-offset wv*4 (16B chunk s=wv>>1, half wv&1)
#define BWRITE(KT, r0, r1, r2, r3)                                       \
  {                                                                      \
    sumsq += r0 * r0 + r1 * r1 + r2 * r2 + r3 * r3;                      \
    uint2 pk_;                                                           \
    pk_.x = (unsigned int)f2bf(r0) | ((unsigned int)f2bf(r1) << 16);     \
    pk_.y = (unsigned int)f2bf(r2) | ((unsigned int)f2bf(r3) << 16);     \
    const int wb_ = bn * 64 +                                            \
                    ((((wv >> 1) ^ (bn & 3) ^ ((bn >> 2) & 3)) << 4) |   \
                     ((wv & 1) << 3));                                   \
    *reinterpret_cast<uint2*>(Bb + ((KT)&1) * 4096 + wb_) = pk_;         \
  }

  // ---- prologue ----
  float c0, c1, c2, c3;  // B(0)
  float p0, p1, p2, p3;  // B(kt+1), loop-carried (single set)
  BLOAD(0, c0, c1, c2, c3);
  FENCE();
  AGLL(0);
  FENCE();
  BLOAD(1, p0, p1, p2, p3);
  FENCE();
  AGLL(1);
  FENCE();
  // queue: [B0:4, A0:4, B1:4, A1:4]
  asm volatile("s_waitcnt vmcnt(12)" ::: "memory");  // B0 landed
  BWRITE(0, c0, c1, c2, c3);
  FENCE();
  asm volatile("s_waitcnt vmcnt(8)" ::: "memory");  // A0 landed -> [B1,A1]
  asm volatile("s_waitcnt lgkmcnt(0)" ::: "memory");
  FENCE();
  __builtin_amdgcn_s_barrier();
  FENCE();

  for (int kt = 0; kt < 16; ++kt) {
    const int cur = kt & 1;
    // 1. fragment ds_reads (A from own region; B from shared tile)
    short8 af[4], bfr[4];
#pragma unroll
    for (int mf = 0; mf < 4; ++mf) {
      const int row = mf * 16 + lr;  // within wave's 64-row region
      af[mf] = *reinterpret_cast<const short8*>(Ab + cur * 32768 + wv * 4096 +
                                                row * 64 + swz);
    }
#pragma unroll
    for (int nf = 0; nf < 4; ++nf) {
      const int n = nf * 16 + lr;
      bfr[nf] = *reinterpret_cast<const short8*>(Bb + cur * 4096 + n * 64 + swz);
    }
    FENCE();
    // 2-4. retire B(kt+1) regs (iter-old), commit them, issue B(kt+2)
    if (kt < 15) {
      asm volatile("s_waitcnt vmcnt(4)" ::: "memory");
      BWRITE(kt + 1, p0, p1, p2, p3);
    }
    if (kt < 14) {
      BLOAD(kt + 2, p0, p1, p2, p3);
    }
    FENCE();
    // 5-6. drain own ds ops (reads for MFMA; BWRITE for barrier), then
    //      refill own A region (WAR-safe: my reads retired)
    asm volatile("s_waitcnt lgkmcnt(0)" ::: "memory");
    FENCE();
    if (kt < 14) {
      AGLL(kt + 2);
      FENCE();
    }
    // 7. MFMA
    __builtin_amdgcn_s_setprio(1);
#pragma unroll
    for (int mf = 0; mf < 4; ++mf)
#pragma unroll
      for (int nf = 0; nf < 4; ++nf)
        acc[mf][nf] = __builtin_amdgcn_mfma_f32_16x16x32_bf16(
            af[mf], bfr[nf], acc[mf][nf], 0, 0, 0);
    __builtin_amdgcn_s_setprio(0);
    FENCE();
    // 8. the single barrier: B writes (drained pre-barrier) -> next readers
    __builtin_amdgcn_s_barrier();
    FENCE();
    // 9. wave-local: ensure A(kt+1) landed for next iter's reads
    if (kt < 14) {
      asm volatile("s_waitcnt vmcnt(8)" ::: "memory");
    } else if (kt == 14) {
      asm volatile("s_waitcnt vmcnt(0)" ::: "memory");
    }
    FENCE();
  }

  // ---- column-norm reduce ----
  atomicAdd(&colsq[bn], sumsq);
  asm volatile("s_waitcnt lgkmcnt(0)" ::: "memory");
  FENCE();
  __builtin_amdgcn_s_barrier();
  FENCE();

  const float tnew = ws_tnew[0];
  float invn[4];
#pragma unroll
  for (int nf = 0; nf < 4; ++nf)
    invn[nf] = rsqrtf(fmaxf(colsq[nf * 16 + lr], 1e-30f));

  // ---- epilogue: transpose through wave-private LDS, float4 stores ----
  float* est = reinterpret_cast<float*>(Alds) + (size_t)wv * 1088;  // 16x68
  const int c4 = n0 + lr * 4;
#pragma unroll
  for (int mf = 0; mf < 4; ++mf) {
    asm volatile("s_waitcnt lgkmcnt(0)" ::: "memory");  // WAR vs prev reads
    FENCE();
#pragma unroll
    for (int r = 0; r < 4; ++r)
#pragma unroll
      for (int nf = 0; nf < 4; ++nf)
        est[(lg * 4 + r) * 68 + nf * 16 + lr] = acc[mf][nf][r] * invn[nf];
    asm volatile("s_waitcnt lgkmcnt(0)" ::: "memory");  // RAW: writes visible
    FENCE();
#pragma unroll
    for (int p = 0; p < 4; ++p) {
      const int rr = p * 4 + lg;
      const int m = wv * 64 + mf * 16 + rr;
      const float ctm = ws_ctm[m];
      const float ft = ws_ft[m];
      const int lab = label[m];
      float4 vv = *reinterpret_cast<const float4*>(&est[rr * 68 + lr * 4]);
      if (c4 < CC) {
        float ov[4] = {vv.x, vv.y, vv.z, vv.w};
#pragma unroll
        for (int j = 0; j < 4; ++j) {
          float cosv = fminf(fmaxf(ov[j], -1.f), 1.f);
          float val = (cosv > ctm) ? cosv * (tnew + cosv) : cosv;
          if (c4 + j == lab) val = ft;
          ov[j] = val * S_SCALE;
        }
        float4 st4;
        st4.x = ov[0]; st4.y = ov[1]; st4.z = ov[2]; st4.w = ov[3];
        *reinterpret_cast<float4*>(out + (size_t)m * CC + c4) = st4;
      }
    }
  }
#undef BLOAD
#undef AGLL
#undef BWRITE
}

// ---------------------------------------------------------------------------
extern "C" void kernel_launch(void* const* d_in, const int* in_sizes, int n_in,
                              void* d_out, int out_size, void* d_ws,
                              size_t ws_size, hipStream_t stream) {
  (void)in_sizes; (void)n_in; (void)out_size; (void)ws_size;
  const float* emb = (const float*)d_in[0];
  const float* kern = (const float*)d_in[1];
  const int* label = (const int*)d_in[2];
  const float* t_in = (const float*)d_in[3];
  float* out = (float*)d_out;

  char* ws = (char*)d_ws;
  unsigned short* wsA = (unsigned short*)ws;
  float* ws_target = (float*)(ws + 524288);
  float* ws_ctm = (float*)(ws + 526336);
  float* ws_ft = (float*)(ws + 528384);
  float* ws_tnew = (float*)(ws + 530432);

  k1_prep<<<512, 64, 0, stream>>>(emb, kern, label, wsA, ws_target, ws_ctm, ws_ft);
  k2_tnew<<<1, 64, 0, stream>>>(ws_target, t_in, ws_tnew);
  k3_gemm<<<(CC + 63) / 64, 512, 0, stream>>>(kern, wsA, label, ws_ctm, ws_ft,
                                              ws_tnew, out);
}